// Round 12
// baseline (296.107 us; speedup 1.0000x reference)
//
#include <hip/hip_runtime.h>
#include <hip/hip_bf16.h>
#include <math.h>

#define IMG_H 192
#define IMG_W 192
#define NPIX (IMG_H * IMG_W)      // 36864
#define PADW 194
#define PPIX (PADW * PADW)        // 37636
#define PH 208                    // deform-sample padded plane (offset +6)
#define PW 208

typedef _Float16 h8 __attribute__((ext_vector_type(8)));
typedef _Float16 h4 __attribute__((ext_vector_type(4)));
typedef float f32x4 __attribute__((ext_vector_type(4)));

__device__ __forceinline__ float act_tanh5(float x) {
    const float t = __expf(2.f * x);
    return 5.f * (t - 1.f) / (t + 1.f);
}
__device__ __forceinline__ float act_sig(float x) {
    return 1.f / (1.f + __expf(-x));
}

// ---------------------------------------------------------------------------
// Async global->LDS 16B copy (global_load_lds_dwordx4). LDS destination is
// wave-uniform base + lane*16 — callers pass a wave-uniform lds pointer.
// ---------------------------------------------------------------------------
typedef __attribute__((address_space(1))) const unsigned int GU32;
typedef __attribute__((address_space(3))) unsigned int LU32;
__device__ __forceinline__ void cp16(const void* g, void* l) {
    __builtin_amdgcn_global_load_lds((GU32*)g, (LU32*)l, 16, 0, 0);
}

// ---------------------------------------------------------------------------
// Weight pack helper: fp32 [co][CIN][3][3] -> fp16 [chunk][k][co<COP][ci32]
// ---------------------------------------------------------------------------
template<int CIN, int COP, int COUT>
__device__ __forceinline__ void pack_body(
    int bx, const float* __restrict__ src, _Float16* __restrict__ dst)
{
    const int chunk = bx / 9, k = bx % 9;
    for (int i = threadIdx.x; i < COP * 32; i += 256) {
        const int co = i >> 5, cil = i & 31;
        float v = 0.f;
        if (co < COUT)
            v = src[((size_t)(co * CIN + chunk * 32 + cil)) * 9 + k];
        dst[(size_t)bx * COP * 32 + i] = (_Float16)v;
    }
}

// ---------------------------------------------------------------------------
// R8: ALL prep work fused into one kernel. Segments by blockIdx:
//   A [0,1164):    cond fp32 planar -> act fmt fp16 [6][PPIX][32], zero ring
//   C [1164,4236): x fp32 -> group-blocked NHWC fp16 xg[16][PH][PW][8] interior
//   B [4236,4344): conv weight packs (w1..w4)
//   D [4344,4728): deform weight pack wdg[16][64][96]
//   E [4728,5128): xg pad-ring zero
//   F [5128,5201): pb1-3 pad-ring zero
// ---------------------------------------------------------------------------
__global__ __launch_bounds__(256) void prep_all_k(
    const float* __restrict__ cond, const float* __restrict__ w1,
    const float* __restrict__ w2, const float* __restrict__ w3,
    const float* __restrict__ w4, const float* __restrict__ x,
    const float* __restrict__ weight,
    _Float16* __restrict__ act_cond, _Float16* __restrict__ wp1,
    _Float16* __restrict__ wp2, _Float16* __restrict__ wp3,
    _Float16* __restrict__ wp4, _Float16* __restrict__ xg,
    _Float16* __restrict__ wdg, _Float16* __restrict__ pb_all)
{
    int b = blockIdx.x;
    const int t = threadIdx.x;

    if (b < 1164) {   // ---- A: cond pack ----
        const int y = b % 194;     // 0..193
        const int c = b / 194;     // chunk 0..5
        if (t >= PADW) return;
        const bool inb = (y >= 1 && y <= IMG_H && t >= 1 && t <= IMG_W);
        h8 v[4];
#pragma unroll
        for (int j = 0; j < 32; j++)
            ((_Float16*)v)[j] = inb
                ? (_Float16)cond[(size_t)(c * 32 + j) * NPIX + (y - 1) * IMG_W + (t - 1)]
                : (_Float16)0.f;
        h8* d = (h8*)&act_cond[((size_t)c * PPIX + (size_t)y * PADW + t) * 32];
        d[0] = v[0]; d[1] = v[1]; d[2] = v[2]; d[3] = v[3];
        return;
    }
    b -= 1164;

    if (b < 3072) {   // ---- C: xg interior ----
        const int y  = b % 192;
        const int dg = b / 192;
        if (t < 192) {
            h8 v;
#pragma unroll
            for (int chl = 0; chl < 8; chl++)
                v[chl] = (_Float16)x[(size_t)(dg * 8 + chl) * NPIX + y * IMG_W + t];
            *(h8*)&xg[(((size_t)dg * PH + y + 6) * PW + t + 6) * 8] = v;
        }
        return;
    }
    b -= 3072;

    if (b < 108) {    // ---- B: conv weight packs ----
        if      (b < 54) pack_body<192, 64, 64>(b, w1, wp1);
        else if (b < 72) pack_body<64, 64, 64>(b - 54, w2, wp2);
        else if (b < 90) pack_body<64, 64, 64>(b - 72, w3, wp3);
        else             pack_body<64, 448, 432>(b - 90, w4, wp4);
        return;
    }
    b -= 108;

    if (b < 384) {    // ---- D: wdg pack ----
        const int i = b * 256 + t;
        if (i < 16 * 64 * 96) {
            const int ks = i % 96;
            const int rest = i / 96;
            const int co = rest % 64;
            const int dg = rest / 64;
            const int k = ks >> 3, chl = ks & 7;
            float v = 0.f;
            if (ks < 72)
                v = weight[((size_t)co * 128 + dg * 8 + chl) * 9 + k];
            wdg[i] = (_Float16)v;
        }
        return;
    }
    b -= 384;

    if (b < 400) {    // ---- E: xg pad-ring zero (6400 ring px per dg) ----
        const int idx = b * 256 + t;
        if (idx < 16 * 6400) {
            const int dg = idx / 6400;
            int r = idx % 6400;
            int row, col;
            if (r < 1248)      { row = r / 208;              col = r % 208; }
            else if (r < 3328) { r -= 1248; row = 198 + r / 208; col = r % 208; }
            else if (r < 4480) { r -= 3328; row = 6 + r / 6;     col = r % 6; }
            else               { r -= 4480; row = 6 + r / 10;    col = 198 + r % 10; }
            h8 z = {0, 0, 0, 0, 0, 0, 0, 0};
            *(h8*)&xg[(((size_t)dg * PH + row) * PW + col) * 8] = z;
        }
        return;
    }
    b -= 400;

    {                 // ---- F: pb1-3 pad-ring zero (772 px x 6 planes x 4 h8) ----
        const int idx = b * 256 + t;
        if (idx < 6 * 772 * 4) {
            const int px_id = idx >> 2, part = idx & 3;
            const int plane = px_id / 772;
            int r = px_id % 772;
            int y, xx;
            if (r < 194)      { y = 0;            xx = r; }
            else if (r < 388) { y = 193;          xx = r - 194; }
            else if (r < 580) { y = 1 + (r - 388); xx = 0; }
            else              { y = 1 + (r - 580); xx = 193; }
            h8 z = {0, 0, 0, 0, 0, 0, 0, 0};
            *(h8*)&pb_all[((size_t)plane * PPIX + (size_t)y * PADW + xx) * 32 + part * 8] = z;
        }
        return;
    }
}

// ---------------------------------------------------------------------------
// m97-style MFMA conv3x3. R11: w_lds ELIMINATED — A-fragments are loaded
// global->VGPR directly. Per wave, af[m] covers a contiguous coalesced 1 KB
// of wpk (lane l: addr = (l&15)*64 + (l>>4)*16 within the (k,m) row-block),
// L2-resident, no barrier interaction; loads overlap MFMA. This removes
// 9 cp16/thread/chunk of weight staging, shrinks the vmcnt(0) drain to the
// input tile only, and cuts LDS 57.9->20.7 KB (conv4) / 43.3->6.4 KB
// (conv1-3) so residency rises 2->~4 blocks/CU for conv4 (the measured
// limiter: MfmaUtil 13%, Occupancy 18%, staging-drain-bound).
// ACT 1: lrelu -> act-format out. ACT 2: ACTIVATED head (tanh5/sigmoid),
// fp16 seg-major [seg][432][32].
// ---------------------------------------------------------------------------
template<int CHUNKS, int ACT, int COP, int T8>
__global__ __launch_bounds__(256, 3) void conv_lds_k(
    const _Float16* __restrict__ in,    // [CHUNKS][PPIX][32]
    const _Float16* __restrict__ wpk,   // [CHUNKS][9][COP][32]
    const float* __restrict__ bias,
    _Float16* __restrict__ out)
{
    constexpr int HALO = T8 ? 10 : 18;
    constexpr int NF   = T8 ? 1 : 4;
    constexpr int TDIM = T8 ? 24 : 12;
    constexpr int TSZ  = T8 ? 8 : 16;
    constexpr int INU  = HALO * HALO * 4;   // 16B units in input tile
    constexpr int ROWU = HALO * 4;          // 16B units per halo row

    __shared__ _Float16 in_lds[HALO * HALO * 32];

    const int t    = threadIdx.x;
    const int lane = t & 63;
    const int wv   = __builtin_amdgcn_readfirstlane(t >> 6);
    const int col  = lane & 15;
    const int quad = lane >> 4;
    const int bx   = blockIdx.x;
    const int tx0  = (bx % TDIM) * TSZ;
    const int ty0  = (bx / TDIM) * TSZ;
    const int cobase = blockIdx.y * 64;

    f32x4 acc[4][NF];
#pragma unroll
    for (int m = 0; m < 4; m++)
#pragma unroll
        for (int s = 0; s < NF; s++) {
            f32x4 z = {0.f, 0.f, 0.f, 0.f};
            acc[m][s] = z;
        }

    for (int c = 0; c < CHUNKS; c++) {
        __syncthreads();   // previous chunk's LDS reads done
        // ---- async stage input halo tile (row-contiguous 16B units) ----
        {
            const char* gbase = (const char*)in + (size_t)c * PPIX * 64;
            char* lbase = (char*)in_lds + (size_t)wv * 64 * 16;
#pragma unroll
            for (int i = 0; i < (INU + 255) / 256; i++) {
                const int j = t + i * 256;
                if (j < INU) {
                    const int row = j / ROWU;
                    const int u   = j - row * ROWU;
                    cp16(gbase + ((size_t)(ty0 + row) * PADW + tx0) * 64 + u * 16,
                         lbase + (size_t)i * 256 * 16);
                }
            }
        }
        __syncthreads();   // drains vmcnt(0): staged input visible

        // ---- 9 taps: weights global->VGPR (L2), input from LDS, MFMA ----
#pragma unroll
        for (int k = 0; k < 9; k++) {
            const int ky = k / 3, kx = k % 3;
            const _Float16* wg = wpk + ((size_t)(c * 9 + k) * COP + cobase) * 32;
            h8 af[4];
#pragma unroll
            for (int m = 0; m < 4; m++)
                af[m] = *(const h8*)&wg[(m * 16 + col) * 32 + quad * 8];
            h8 bf[NF];
            if (T8) {
                bf[0] = *(const h8*)&in_lds[
                    ((2 * wv + (col >> 3) + ky) * HALO + (col & 7) + kx) * 32 + quad * 8];
            } else {
#pragma unroll
                for (int s = 0; s < NF; s++)
                    bf[s] = *(const h8*)&in_lds[
                        ((4 * wv + s + ky) * HALO + col + kx) * 32 + quad * 8];
            }
#pragma unroll
            for (int m = 0; m < 4; m++)
#pragma unroll
                for (int s = 0; s < NF; s++)
                    acc[m][s] = __builtin_amdgcn_mfma_f32_16x16x32_f16(
                        af[m], bf[s], acc[m][s], 0, 0, 0);
        }
    }

    // ---- epilogue: D col = px, D row = co (quad*4+r) ----
#pragma unroll
    for (int m = 0; m < 4; m++) {
#pragma unroll
        for (int s = 0; s < NF; s++) {
            int gy, gx;
            if (T8) { gy = ty0 + 2 * wv + (col >> 3); gx = tx0 + (col & 7); }
            else    { gy = ty0 + 4 * wv + s;          gx = tx0 + col; }
            const int ca = cobase + m * 16 + quad * 4;   // first of 4 co
            if (ACT == 1) {
                h4 st;
#pragma unroll
                for (int r = 0; r < 4; r++) {
                    float v = acc[m][s][r] + bias[ca + r];
                    st[r] = (_Float16)((v >= 0.f) ? v : 0.1f * v);
                }
                *(h4*)&out[((size_t)(ca >> 5) * PPIX + (size_t)(gy + 1) * PADW + (gx + 1)) * 32
                           + (ca & 31)] = st;
            } else {
#pragma unroll
                for (int r = 0; r < 4; r++) {
                    const int co = ca + r;
                    if (co < 432) {  // ACTIVATED head, fp16 segment-major
                        const int pix = gy * IMG_W + gx;
                        float v = acc[m][s][r] + bias[co];
                        v = (ca < 288) ? act_tanh5(v) : act_sig(v);
                        out[((size_t)(pix >> 5) * 432 + co) * 32 + (pix & 31)] =
                            (_Float16)v;
                    }
                }
            }
        }
    }
}

// ---------------------------------------------------------------------------
// Deformable conv, MFMA version. R10 structure (best measured): 256t,
// 2 barriers/dq, val4 26.6 KB, XCD swizzle, direct seg-major PRE-ACTIVATED
// od reads, global xg gathers. Issue/latency-bound at ~46-50 us (TLP-null
// R4, ILP-null R6, bytes-null R5/R7, LDS-window regressed R9).
// ---------------------------------------------------------------------------
__global__ __launch_bounds__(256) void deform_mfma_k(
    const _Float16* __restrict__ xg,   // [16][PH][PW][8]
    const _Float16* __restrict__ od,   // [1152 seg][432 co][32 px] ACTIVATED
    const _Float16* __restrict__ wdg,  // [16][64][96]
    const float* __restrict__ bias,
    float* __restrict__ out)
{
    __shared__ __align__(16) _Float16 val4[4][32][104];   // 26.6 KB

    const int t    = threadIdx.x;
    const int lane = t & 63;
    const int wv   = __builtin_amdgcn_readfirstlane(t >> 6);
    const int col  = lane & 15;
    const int quad = lane >> 4;
    const int bxr  = blockIdx.x;                    // raw
    const int bx   = (bxr & 7) * 144 + (bxr >> 3);  // XCD-chunked seg id
    const int gy   = bx / 6;
    const int gx0  = (bx % 6) * 32;

    const _Float16* odseg = od + (size_t)bx * 432 * 32;

    // zero pad tail [72..104) once (read range is [0..96))
    for (int i = t; i < 4 * 32 * 4; i += 256) {
        const int dgl = i >> 7;
        const int r   = i & 127;
        const int px  = r >> 2;
        const int j   = r & 3;
        h8 z = {0, 0, 0, 0, 0, 0, 0, 0};
        *(h8*)&val4[dgl][px][72 + 8 * j] = z;
    }

    f32x4 acc[2];
    {
        f32x4 z = {0.f, 0.f, 0.f, 0.f};
        acc[0] = z; acc[1] = z;
    }

    for (int dq = 0; dq < 4; dq++) {
        __syncthreads();   // prev chunk's val4 reads done (covers init too)

        // ---- sampling: od pre-activated (direct reads), xg gathers ----
        for (int idx = t; idx < 1152; idx += 256) {
            const int pxl  = idx & 31;
            const int rest = idx >> 5;      // 0..35
            const int k    = rest % 9;
            const int dgl  = rest / 9;
            const int dg   = dq * 4 + dgl;
            const int rr   = dgl * 9 + k;
            const float oy = (float)odseg[(dq * 72 + 2 * rr) * 32 + pxl];
            const float ox = (float)odseg[(dq * 72 + 2 * rr + 1) * 32 + pxl];
            const float m  = (float)odseg[(288 + dq * 36 + rr) * 32 + pxl];
            const float py  = (float)(gy - 1 + k / 3) + oy;
            const float pxx = (float)(gx0 + pxl - 1 + k % 3) + ox;
            const float y0 = floorf(py), x0 = floorf(pxx);
            const float fy = py - y0, fx = pxx - x0;
            const int iy = (int)y0 + 6, ix = (int)x0 + 6;
            const _Float16* p = xg + (((size_t)dg * PH + iy) * PW + ix) * 8;
            const h8 c00 = *(const h8*)p;
            const h8 c01 = *(const h8*)(p + 8);
            const h8 c10 = *(const h8*)(p + PW * 8);
            const h8 c11 = *(const h8*)(p + PW * 8 + 8);
            const float ey = 1.f - fy, ex = 1.f - fx;
            const _Float16 s00 = (_Float16)(ey * ex * m);
            const _Float16 s01 = (_Float16)(ey * fx * m);
            const _Float16 s10 = (_Float16)(fy * ex * m);
            const _Float16 s11 = (_Float16)(fy * fx * m);
            const h8 v = c00 * s00 + c01 * s01 + c10 * s10 + c11 * s11;
            *(h8*)&val4[dgl][pxl][k * 8] = v;
        }
        __syncthreads();

        // ---- MFMA: 4 dgl x 3 ks x 2 px-frags ----
#pragma unroll
        for (int dgl = 0; dgl < 4; dgl++) {
            const int dg = dq * 4 + dgl;
            const _Float16* wbase = wdg + ((size_t)dg * 64 + wv * 16 + col) * 96;
#pragma unroll
            for (int ks = 0; ks < 3; ks++) {
                const h8 a  = *(const h8*)(wbase + ks * 32 + quad * 8);
                const h8 b0 = *(const h8*)&val4[dgl][col][ks * 32 + quad * 8];
                const h8 b1 = *(const h8*)&val4[dgl][16 + col][ks * 32 + quad * 8];
                acc[0] = __builtin_amdgcn_mfma_f32_16x16x32_f16(a, b0, acc[0], 0, 0, 0);
                acc[1] = __builtin_amdgcn_mfma_f32_16x16x32_f16(a, b1, acc[1], 0, 0, 0);
            }
        }
    }

    const int co = wv * 16 + quad * 4;
#pragma unroll
    for (int n = 0; n < 2; n++) {
        const int gx = gx0 + n * 16 + col;
#pragma unroll
        for (int r = 0; r < 4; r++)
            out[(size_t)(co + r) * NPIX + gy * IMG_W + gx] = acc[n][r] + bias[co + r];
    }
}

// ---------------------------------------------------------------------------
// Launch: 6 dispatches.
// ---------------------------------------------------------------------------
extern "C" void kernel_launch(void* const* d_in, const int* in_sizes, int n_in,
                              void* d_out, int out_size, void* d_ws, size_t ws_size,
                              hipStream_t stream) {
    (void)in_sizes; (void)n_in; (void)out_size; (void)ws_size;

    const float* x      = (const float*)d_in[0];
    const float* cond   = (const float*)d_in[1];
    const float* weight = (const float*)d_in[2];
    const float* bias   = (const float*)d_in[3];
    const float* w1     = (const float*)d_in[4];
    const float* b1     = (const float*)d_in[5];
    const float* w2     = (const float*)d_in[6];
    const float* b2     = (const float*)d_in[7];
    const float* w3     = (const float*)d_in[8];
    const float* b3     = (const float*)d_in[9];
    const float* w4     = (const float*)d_in[10];
    const float* b4     = (const float*)d_in[11];
    float* out = (float*)d_out;

    char* ws = (char*)d_ws;
    size_t off = 0;
    auto take = [&](size_t bytes) -> char* {
        char* p = ws + off;
        off = (off + bytes + 255) & ~(size_t)255;
        return p;
    };
    _Float16* act_cond = (_Float16*)take((size_t)6 * PPIX * 32 * 2);  // conv1 in
    _Float16* pb_all   = (_Float16*)take((size_t)3 * 2 * PPIX * 32 * 2);
    _Float16* pb1 = pb_all;                         // conv1 out [2][PPIX][32]
    _Float16* pb2 = pb1 + (size_t)2 * PPIX * 32;    // conv2 out
    _Float16* pb3 = pb2 + (size_t)2 * PPIX * 32;    // conv3 out
    _Float16* od  = (_Float16*)take((size_t)432 * NPIX * 2);  // [1152][432][32]
    _Float16* wp1 = (_Float16*)take((size_t)54 * 64 * 32 * 2);
    _Float16* wp2 = (_Float16*)take((size_t)18 * 64 * 32 * 2);
    _Float16* wp3 = (_Float16*)take((size_t)18 * 64 * 32 * 2);
    _Float16* wp4 = (_Float16*)take((size_t)18 * 448 * 32 * 2);
    _Float16* xg  = (_Float16*)take((size_t)16 * PH * PW * 8 * 2);
    _Float16* wdg = (_Float16*)take((size_t)16 * 64 * 96 * 2);

    // Fused prep: packs + pad-ring zeroing.
    hipLaunchKernelGGL(prep_all_k, dim3(5201), dim3(256), 0, stream,
                       cond, w1, w2, w3, w4, x, weight,
                       act_cond, wp1, wp2, wp3, wp4, xg, wdg, pb_all);

    // conv1-3: 8x8 tiles, 576 blocks. conv4: 16x16 tiles, grid(144,7).
    hipLaunchKernelGGL((conv_lds_k<6, 1, 64, 1>),  dim3(576, 1), dim3(256), 0, stream, act_cond, wp1, b1, pb1);
    hipLaunchKernelGGL((conv_lds_k<2, 1, 64, 1>),  dim3(576, 1), dim3(256), 0, stream, pb1, wp2, b2, pb2);
    hipLaunchKernelGGL((conv_lds_k<2, 1, 64, 1>),  dim3(576, 1), dim3(256), 0, stream, pb2, wp3, b3, pb3);
    hipLaunchKernelGGL((conv_lds_k<2, 2, 448, 0>), dim3(144, 7), dim3(256), 0, stream, pb3, wp4, b4, od);
    hipLaunchKernelGGL(deform_mfma_k, dim3(1152), dim3(256), 0, stream, xg, od, wdg, bias, out);
}

// Round 13
// 241.173 us; speedup vs baseline: 1.2278x; 1.2278x over previous
//
#include <hip/hip_runtime.h>
#include <hip/hip_bf16.h>
#include <math.h>

#define IMG_H 192
#define IMG_W 192
#define NPIX (IMG_H * IMG_W)      // 36864
#define PADW 194
#define PPIX (PADW * PADW)        // 37636
#define PH 208                    // deform-sample padded plane (offset +6)
#define PW 208

typedef _Float16 h8 __attribute__((ext_vector_type(8)));
typedef _Float16 h4 __attribute__((ext_vector_type(4)));
typedef float f32x4 __attribute__((ext_vector_type(4)));

__device__ __forceinline__ float act_tanh5(float x) {
    const float t = __expf(2.f * x);
    return 5.f * (t - 1.f) / (t + 1.f);
}
__device__ __forceinline__ float act_sig(float x) {
    return 1.f / (1.f + __expf(-x));
}

// ---------------------------------------------------------------------------
// Async global->LDS 16B copy (global_load_lds_dwordx4). LDS destination is
// wave-uniform base + lane*16 — callers pass a wave-uniform lds pointer.
// ---------------------------------------------------------------------------
typedef __attribute__((address_space(1))) const unsigned int GU32;
typedef __attribute__((address_space(3))) unsigned int LU32;
__device__ __forceinline__ void cp16(const void* g, void* l) {
    __builtin_amdgcn_global_load_lds((GU32*)g, (LU32*)l, 16, 0, 0);
}

// ---------------------------------------------------------------------------
// Weight pack helper: fp32 [co][CIN][3][3] -> fp16 [chunk][k][co<COP][ci32]
// ---------------------------------------------------------------------------
template<int CIN, int COP, int COUT>
__device__ __forceinline__ void pack_body(
    int bx, const float* __restrict__ src, _Float16* __restrict__ dst)
{
    const int chunk = bx / 9, k = bx % 9;
    for (int i = threadIdx.x; i < COP * 32; i += 256) {
        const int co = i >> 5, cil = i & 31;
        float v = 0.f;
        if (co < COUT)
            v = src[((size_t)(co * CIN + chunk * 32 + cil)) * 9 + k];
        dst[(size_t)bx * COP * 32 + i] = (_Float16)v;
    }
}

// ---------------------------------------------------------------------------
// R8: ALL prep work fused into one kernel. Segments by blockIdx:
//   A [0,1164):    cond fp32 planar -> act fmt fp16 [6][PPIX][32], zero ring
//   C [1164,4236): x fp32 -> group-blocked NHWC fp16 xg[16][PH][PW][8] interior
//   B [4236,4344): conv weight packs (w1..w4)
//   D [4344,4728): deform weight pack wdg[16][64][96]
//   E [4728,5128): xg pad-ring zero
//   F [5128,5201): pb1-3 pad-ring zero
// ---------------------------------------------------------------------------
__global__ __launch_bounds__(256) void prep_all_k(
    const float* __restrict__ cond, const float* __restrict__ w1,
    const float* __restrict__ w2, const float* __restrict__ w3,
    const float* __restrict__ w4, const float* __restrict__ x,
    const float* __restrict__ weight,
    _Float16* __restrict__ act_cond, _Float16* __restrict__ wp1,
    _Float16* __restrict__ wp2, _Float16* __restrict__ wp3,
    _Float16* __restrict__ wp4, _Float16* __restrict__ xg,
    _Float16* __restrict__ wdg, _Float16* __restrict__ pb_all)
{
    int b = blockIdx.x;
    const int t = threadIdx.x;

    if (b < 1164) {   // ---- A: cond pack ----
        const int y = b % 194;     // 0..193
        const int c = b / 194;     // chunk 0..5
        if (t >= PADW) return;
        const bool inb = (y >= 1 && y <= IMG_H && t >= 1 && t <= IMG_W);
        h8 v[4];
#pragma unroll
        for (int j = 0; j < 32; j++)
            ((_Float16*)v)[j] = inb
                ? (_Float16)cond[(size_t)(c * 32 + j) * NPIX + (y - 1) * IMG_W + (t - 1)]
                : (_Float16)0.f;
        h8* d = (h8*)&act_cond[((size_t)c * PPIX + (size_t)y * PADW + t) * 32];
        d[0] = v[0]; d[1] = v[1]; d[2] = v[2]; d[3] = v[3];
        return;
    }
    b -= 1164;

    if (b < 3072) {   // ---- C: xg interior ----
        const int y  = b % 192;
        const int dg = b / 192;
        if (t < 192) {
            h8 v;
#pragma unroll
            for (int chl = 0; chl < 8; chl++)
                v[chl] = (_Float16)x[(size_t)(dg * 8 + chl) * NPIX + y * IMG_W + t];
            *(h8*)&xg[(((size_t)dg * PH + y + 6) * PW + t + 6) * 8] = v;
        }
        return;
    }
    b -= 3072;

    if (b < 108) {    // ---- B: conv weight packs ----
        if      (b < 54) pack_body<192, 64, 64>(b, w1, wp1);
        else if (b < 72) pack_body<64, 64, 64>(b - 54, w2, wp2);
        else if (b < 90) pack_body<64, 64, 64>(b - 72, w3, wp3);
        else             pack_body<64, 448, 432>(b - 90, w4, wp4);
        return;
    }
    b -= 108;

    if (b < 384) {    // ---- D: wdg pack ----
        const int i = b * 256 + t;
        if (i < 16 * 64 * 96) {
            const int ks = i % 96;
            const int rest = i / 96;
            const int co = rest % 64;
            const int dg = rest / 64;
            const int k = ks >> 3, chl = ks & 7;
            float v = 0.f;
            if (ks < 72)
                v = weight[((size_t)co * 128 + dg * 8 + chl) * 9 + k];
            wdg[i] = (_Float16)v;
        }
        return;
    }
    b -= 384;

    if (b < 400) {    // ---- E: xg pad-ring zero (6400 ring px per dg) ----
        const int idx = b * 256 + t;
        if (idx < 16 * 6400) {
            const int dg = idx / 6400;
            int r = idx % 6400;
            int row, col;
            if (r < 1248)      { row = r / 208;              col = r % 208; }
            else if (r < 3328) { r -= 1248; row = 198 + r / 208; col = r % 208; }
            else if (r < 4480) { r -= 3328; row = 6 + r / 6;     col = r % 6; }
            else               { r -= 4480; row = 6 + r / 10;    col = 198 + r % 10; }
            h8 z = {0, 0, 0, 0, 0, 0, 0, 0};
            *(h8*)&xg[(((size_t)dg * PH + row) * PW + col) * 8] = z;
        }
        return;
    }
    b -= 400;

    {                 // ---- F: pb1-3 pad-ring zero (772 px x 6 planes x 4 h8) ----
        const int idx = b * 256 + t;
        if (idx < 6 * 772 * 4) {
            const int px_id = idx >> 2, part = idx & 3;
            const int plane = px_id / 772;
            int r = px_id % 772;
            int y, xx;
            if (r < 194)      { y = 0;            xx = r; }
            else if (r < 388) { y = 193;          xx = r - 194; }
            else if (r < 580) { y = 1 + (r - 388); xx = 0; }
            else              { y = 1 + (r - 580); xx = 193; }
            h8 z = {0, 0, 0, 0, 0, 0, 0, 0};
            *(h8*)&pb_all[((size_t)plane * PPIX + (size_t)y * PADW + xx) * 32 + part * 8] = z;
        }
        return;
    }
}

// ---------------------------------------------------------------------------
// m97-style MFMA conv3x3. R13: REVERTED to R10's w_lds version (R12's
// global-weight path put L2 latency on the MFMA chain: 52.4 -> 65.3 us).
// Weights stage async into LDS once per chunk, off the critical path.
// NEW (R13): XCD-chunked bijective bx swizzle (T1; grids 144=8x18 and
// 576=8x72) — each XCD works a contiguous row-band whose input slice fits
// its private 4MB L2. Pure index permutation, outputs bit-identical.
// ACT 1: lrelu -> act-format out. ACT 2: ACTIVATED head (tanh5/sigmoid),
// fp16 seg-major [seg][432][32].
// ---------------------------------------------------------------------------
template<int CHUNKS, int ACT, int COP, int T8>
__global__ __launch_bounds__(256) void conv_lds_k(
    const _Float16* __restrict__ in,    // [CHUNKS][PPIX][32]
    const _Float16* __restrict__ wpk,   // [CHUNKS][9][COP][32]
    const float* __restrict__ bias,
    _Float16* __restrict__ out)
{
    constexpr int HALO = T8 ? 10 : 18;
    constexpr int NF   = T8 ? 1 : 4;
    constexpr int TDIM = T8 ? 24 : 12;
    constexpr int TSZ  = T8 ? 8 : 16;
    constexpr int INU  = HALO * HALO * 4;   // 16B units in input tile
    constexpr int ROWU = HALO * 4;          // 16B units per halo row
    constexpr int CPX  = (T8 ? 576 : 144) / 8;   // blocks per XCD chunk

    __shared__ _Float16 in_lds[HALO * HALO * 32];
    __shared__ _Float16 w_lds[9 * 64 * 32];

    const int t    = threadIdx.x;
    const int lane = t & 63;
    const int wv   = __builtin_amdgcn_readfirstlane(t >> 6);
    const int col  = lane & 15;
    const int quad = lane >> 4;
    const int bxr  = blockIdx.x;
    const int bx   = (bxr & 7) * CPX + (bxr >> 3);   // XCD-chunked
    const int tx0  = (bx % TDIM) * TSZ;
    const int ty0  = (bx / TDIM) * TSZ;
    const int cobase = blockIdx.y * 64;

    f32x4 acc[4][NF];
#pragma unroll
    for (int m = 0; m < 4; m++)
#pragma unroll
        for (int s = 0; s < NF; s++) {
            f32x4 z = {0.f, 0.f, 0.f, 0.f};
            acc[m][s] = z;
        }

    for (int c = 0; c < CHUNKS; c++) {
        __syncthreads();   // previous chunk's LDS reads done
        // ---- async stage input halo tile (row-contiguous 16B units) ----
        {
            const char* gbase = (const char*)in + (size_t)c * PPIX * 64;
            char* lbase = (char*)in_lds + (size_t)wv * 64 * 16;
#pragma unroll
            for (int i = 0; i < (INU + 255) / 256; i++) {
                const int j = t + i * 256;
                if (j < INU) {
                    const int row = j / ROWU;
                    const int u   = j - row * ROWU;
                    cp16(gbase + ((size_t)(ty0 + row) * PADW + tx0) * 64 + u * 16,
                         lbase + (size_t)i * 256 * 16);
                }
            }
        }
        // ---- async stage weights: 9 taps x 64co x 64B (contiguous) ----
        {
            const char* gw = (const char*)wpk
                + ((size_t)(c * 9) * COP + cobase) * 64 + t * 16;
            char* lw = (char*)w_lds + (size_t)wv * 64 * 16;
#pragma unroll
            for (int k = 0; k < 9; k++)
                cp16(gw + (size_t)k * COP * 64, lw + k * 4096);
        }
        __syncthreads();   // drains vmcnt(0): staged data visible

        // ---- 9 taps: pure LDS + MFMA ----
#pragma unroll
        for (int k = 0; k < 9; k++) {
            const int ky = k / 3, kx = k % 3;
            h8 af[4];
#pragma unroll
            for (int m = 0; m < 4; m++)
                af[m] = *(const h8*)&w_lds[(k * 64 + m * 16 + col) * 32 + quad * 8];
            h8 bf[NF];
            if (T8) {
                bf[0] = *(const h8*)&in_lds[
                    ((2 * wv + (col >> 3) + ky) * HALO + (col & 7) + kx) * 32 + quad * 8];
            } else {
#pragma unroll
                for (int s = 0; s < NF; s++)
                    bf[s] = *(const h8*)&in_lds[
                        ((4 * wv + s + ky) * HALO + col + kx) * 32 + quad * 8];
            }
#pragma unroll
            for (int m = 0; m < 4; m++)
#pragma unroll
                for (int s = 0; s < NF; s++)
                    acc[m][s] = __builtin_amdgcn_mfma_f32_16x16x32_f16(
                        af[m], bf[s], acc[m][s], 0, 0, 0);
        }
    }

    // ---- epilogue: D col = px, D row = co (quad*4+r) ----
#pragma unroll
    for (int m = 0; m < 4; m++) {
#pragma unroll
        for (int s = 0; s < NF; s++) {
            int gy, gx;
            if (T8) { gy = ty0 + 2 * wv + (col >> 3); gx = tx0 + (col & 7); }
            else    { gy = ty0 + 4 * wv + s;          gx = tx0 + col; }
            const int ca = cobase + m * 16 + quad * 4;   // first of 4 co
            if (ACT == 1) {
                h4 st;
#pragma unroll
                for (int r = 0; r < 4; r++) {
                    float v = acc[m][s][r] + bias[ca + r];
                    st[r] = (_Float16)((v >= 0.f) ? v : 0.1f * v);
                }
                *(h4*)&out[((size_t)(ca >> 5) * PPIX + (size_t)(gy + 1) * PADW + (gx + 1)) * 32
                           + (ca & 31)] = st;
            } else {
#pragma unroll
                for (int r = 0; r < 4; r++) {
                    const int co = ca + r;
                    if (co < 432) {  // ACTIVATED head, fp16 segment-major
                        const int pix = gy * IMG_W + gx;
                        float v = acc[m][s][r] + bias[co];
                        v = (ca < 288) ? act_tanh5(v) : act_sig(v);
                        out[((size_t)(pix >> 5) * 432 + co) * 32 + (pix & 31)] =
                            (_Float16)v;
                    }
                }
            }
        }
    }
}

// ---------------------------------------------------------------------------
// Deformable conv, MFMA version. R10 structure (best measured): 256t,
// 2 barriers/dq, val4 26.6 KB, XCD swizzle, direct seg-major PRE-ACTIVATED
// od reads, global xg gathers. Issue/latency-bound at ~46-50 us (TLP-null
// R4, ILP-null R6, bytes-null R5/R7, LDS-window regressed R9).
// ---------------------------------------------------------------------------
__global__ __launch_bounds__(256) void deform_mfma_k(
    const _Float16* __restrict__ xg,   // [16][PH][PW][8]
    const _Float16* __restrict__ od,   // [1152 seg][432 co][32 px] ACTIVATED
    const _Float16* __restrict__ wdg,  // [16][64][96]
    const float* __restrict__ bias,
    float* __restrict__ out)
{
    __shared__ __align__(16) _Float16 val4[4][32][104];   // 26.6 KB

    const int t    = threadIdx.x;
    const int lane = t & 63;
    const int wv   = __builtin_amdgcn_readfirstlane(t >> 6);
    const int col  = lane & 15;
    const int quad = lane >> 4;
    const int bxr  = blockIdx.x;                    // raw
    const int bx   = (bxr & 7) * 144 + (bxr >> 3);  // XCD-chunked seg id
    const int gy   = bx / 6;
    const int gx0  = (bx % 6) * 32;

    const _Float16* odseg = od + (size_t)bx * 432 * 32;

    // zero pad tail [72..104) once (read range is [0..96))
    for (int i = t; i < 4 * 32 * 4; i += 256) {
        const int dgl = i >> 7;
        const int r   = i & 127;
        const int px  = r >> 2;
        const int j   = r & 3;
        h8 z = {0, 0, 0, 0, 0, 0, 0, 0};
        *(h8*)&val4[dgl][px][72 + 8 * j] = z;
    }

    f32x4 acc[2];
    {
        f32x4 z = {0.f, 0.f, 0.f, 0.f};
        acc[0] = z; acc[1] = z;
    }

    for (int dq = 0; dq < 4; dq++) {
        __syncthreads();   // prev chunk's val4 reads done (covers init too)

        // ---- sampling: od pre-activated (direct reads), xg gathers ----
        for (int idx = t; idx < 1152; idx += 256) {
            const int pxl  = idx & 31;
            const int rest = idx >> 5;      // 0..35
            const int k    = rest % 9;
            const int dgl  = rest / 9;
            const int dg   = dq * 4 + dgl;
            const int rr   = dgl * 9 + k;
            const float oy = (float)odseg[(dq * 72 + 2 * rr) * 32 + pxl];
            const float ox = (float)odseg[(dq * 72 + 2 * rr + 1) * 32 + pxl];
            const float m  = (float)odseg[(288 + dq * 36 + rr) * 32 + pxl];
            const float py  = (float)(gy - 1 + k / 3) + oy;
            const float pxx = (float)(gx0 + pxl - 1 + k % 3) + ox;
            const float y0 = floorf(py), x0 = floorf(pxx);
            const float fy = py - y0, fx = pxx - x0;
            const int iy = (int)y0 + 6, ix = (int)x0 + 6;
            const _Float16* p = xg + (((size_t)dg * PH + iy) * PW + ix) * 8;
            const h8 c00 = *(const h8*)p;
            const h8 c01 = *(const h8*)(p + 8);
            const h8 c10 = *(const h8*)(p + PW * 8);
            const h8 c11 = *(const h8*)(p + PW * 8 + 8);
            const float ey = 1.f - fy, ex = 1.f - fx;
            const _Float16 s00 = (_Float16)(ey * ex * m);
            const _Float16 s01 = (_Float16)(ey * fx * m);
            const _Float16 s10 = (_Float16)(fy * ex * m);
            const _Float16 s11 = (_Float16)(fy * fx * m);
            const h8 v = c00 * s00 + c01 * s01 + c10 * s10 + c11 * s11;
            *(h8*)&val4[dgl][pxl][k * 8] = v;
        }
        __syncthreads();

        // ---- MFMA: 4 dgl x 3 ks x 2 px-frags ----
#pragma unroll
        for (int dgl = 0; dgl < 4; dgl++) {
            const int dg = dq * 4 + dgl;
            const _Float16* wbase = wdg + ((size_t)dg * 64 + wv * 16 + col) * 96;
#pragma unroll
            for (int ks = 0; ks < 3; ks++) {
                const h8 a  = *(const h8*)(wbase + ks * 32 + quad * 8);
                const h8 b0 = *(const h8*)&val4[dgl][col][ks * 32 + quad * 8];
                const h8 b1 = *(const h8*)&val4[dgl][16 + col][ks * 32 + quad * 8];
                acc[0] = __builtin_amdgcn_mfma_f32_16x16x32_f16(a, b0, acc[0], 0, 0, 0);
                acc[1] = __builtin_amdgcn_mfma_f32_16x16x32_f16(a, b1, acc[1], 0, 0, 0);
            }
        }
    }

    const int co = wv * 16 + quad * 4;
#pragma unroll
    for (int n = 0; n < 2; n++) {
        const int gx = gx0 + n * 16 + col;
#pragma unroll
        for (int r = 0; r < 4; r++)
            out[(size_t)(co + r) * NPIX + gy * IMG_W + gx] = acc[n][r] + bias[co + r];
    }
}

// ---------------------------------------------------------------------------
// Launch: 6 dispatches.
// ---------------------------------------------------------------------------
extern "C" void kernel_launch(void* const* d_in, const int* in_sizes, int n_in,
                              void* d_out, int out_size, void* d_ws, size_t ws_size,
                              hipStream_t stream) {
    (void)in_sizes; (void)n_in; (void)out_size; (void)ws_size;

    const float* x      = (const float*)d_in[0];
    const float* cond   = (const float*)d_in[1];
    const float* weight = (const float*)d_in[2];
    const float* bias   = (const float*)d_in[3];
    const float* w1     = (const float*)d_in[4];
    const float* b1     = (const float*)d_in[5];
    const float* w2     = (const float*)d_in[6];
    const float* b2     = (const float*)d_in[7];
    const float* w3     = (const float*)d_in[8];
    const float* b3     = (const float*)d_in[9];
    const float* w4     = (const float*)d_in[10];
    const float* b4     = (const float*)d_in[11];
    float* out = (float*)d_out;

    char* ws = (char*)d_ws;
    size_t off = 0;
    auto take = [&](size_t bytes) -> char* {
        char* p = ws + off;
        off = (off + bytes + 255) & ~(size_t)255;
        return p;
    };
    _Float16* act_cond = (_Float16*)take((size_t)6 * PPIX * 32 * 2);  // conv1 in
    _Float16* pb_all   = (_Float16*)take((size_t)3 * 2 * PPIX * 32 * 2);
    _Float16* pb1 = pb_all;                         // conv1 out [2][PPIX][32]
    _Float16* pb2 = pb1 + (size_t)2 * PPIX * 32;    // conv2 out
    _Float16* pb3 = pb2 + (size_t)2 * PPIX * 32;    // conv3 out
    _Float16* od  = (_Float16*)take((size_t)432 * NPIX * 2);  // [1152][432][32]
    _Float16* wp1 = (_Float16*)take((size_t)54 * 64 * 32 * 2);
    _Float16* wp2 = (_Float16*)take((size_t)18 * 64 * 32 * 2);
    _Float16* wp3 = (_Float16*)take((size_t)18 * 64 * 32 * 2);
    _Float16* wp4 = (_Float16*)take((size_t)18 * 448 * 32 * 2);
    _Float16* xg  = (_Float16*)take((size_t)16 * PH * PW * 8 * 2);
    _Float16* wdg = (_Float16*)take((size_t)16 * 64 * 96 * 2);

    // Fused prep: packs + pad-ring zeroing.
    hipLaunchKernelGGL(prep_all_k, dim3(5201), dim3(256), 0, stream,
                       cond, w1, w2, w3, w4, x, weight,
                       act_cond, wp1, wp2, wp3, wp4, xg, wdg, pb_all);

    // conv1-3: 8x8 tiles, 576 blocks. conv4: 16x16 tiles, grid(144,7).
    hipLaunchKernelGGL((conv_lds_k<6, 1, 64, 1>),  dim3(576, 1), dim3(256), 0, stream, act_cond, wp1, b1, pb1);
    hipLaunchKernelGGL((conv_lds_k<2, 1, 64, 1>),  dim3(576, 1), dim3(256), 0, stream, pb1, wp2, b2, pb2);
    hipLaunchKernelGGL((conv_lds_k<2, 1, 64, 1>),  dim3(576, 1), dim3(256), 0, stream, pb2, wp3, b3, pb3);
    hipLaunchKernelGGL((conv_lds_k<2, 2, 448, 0>), dim3(144, 7), dim3(256), 0, stream, pb3, wp4, b4, od);
    hipLaunchKernelGGL(deform_mfma_k, dim3(1152), dim3(256), 0, stream, xg, od, wdg, bias, out);
}

// Round 14
// 234.462 us; speedup vs baseline: 1.2629x; 1.0286x over previous
//
#include <hip/hip_runtime.h>
#include <hip/hip_bf16.h>
#include <math.h>

#define IMG_H 192
#define IMG_W 192
#define NPIX (IMG_H * IMG_W)      // 36864
#define PADW 194
#define PPIX (PADW * PADW)        // 37636
#define PH 208                    // deform-sample padded plane (offset +6)
#define PW 208

typedef _Float16 h8 __attribute__((ext_vector_type(8)));
typedef _Float16 h4 __attribute__((ext_vector_type(4)));
typedef float f32x4 __attribute__((ext_vector_type(4)));

__device__ __forceinline__ float act_tanh5(float x) {
    const float t = __expf(2.f * x);
    return 5.f * (t - 1.f) / (t + 1.f);
}
__device__ __forceinline__ float act_sig(float x) {
    return 1.f / (1.f + __expf(-x));
}

// ---------------------------------------------------------------------------
// Async global->LDS 16B copy (global_load_lds_dwordx4). LDS destination is
// wave-uniform base + lane*16 — callers pass a wave-uniform lds pointer.
// ---------------------------------------------------------------------------
typedef __attribute__((address_space(1))) const unsigned int GU32;
typedef __attribute__((address_space(3))) unsigned int LU32;
__device__ __forceinline__ void cp16(const void* g, void* l) {
    __builtin_amdgcn_global_load_lds((GU32*)g, (LU32*)l, 16, 0, 0);
}

// ---------------------------------------------------------------------------
// Weight pack helper: fp32 [co][CIN][3][3] -> fp16 [chunk][k][co<COP][ci32]
// ---------------------------------------------------------------------------
template<int CIN, int COP, int COUT>
__device__ __forceinline__ void pack_body(
    int bx, const float* __restrict__ src, _Float16* __restrict__ dst)
{
    const int chunk = bx / 9, k = bx % 9;
    for (int i = threadIdx.x; i < COP * 32; i += 256) {
        const int co = i >> 5, cil = i & 31;
        float v = 0.f;
        if (co < COUT)
            v = src[((size_t)(co * CIN + chunk * 32 + cil)) * 9 + k];
        dst[(size_t)bx * COP * 32 + i] = (_Float16)v;
    }
}

// ---------------------------------------------------------------------------
// R8: ALL prep work fused into one kernel. Segments by blockIdx:
//   A [0,1164):    cond fp32 planar -> act fmt fp16 [6][PPIX][32], zero ring
//   C [1164,4236): x fp32 -> group-blocked NHWC fp16 xg[16][PH][PW][8] interior
//   B [4236,4344): conv weight packs (w1..w4)
//   D [4344,4728): deform weight pack wdg[16][64][96]
//   E [4728,5128): xg pad-ring zero
//   F [5128,5201): pb1-3 pad-ring zero
// ---------------------------------------------------------------------------
__global__ __launch_bounds__(256) void prep_all_k(
    const float* __restrict__ cond, const float* __restrict__ w1,
    const float* __restrict__ w2, const float* __restrict__ w3,
    const float* __restrict__ w4, const float* __restrict__ x,
    const float* __restrict__ weight,
    _Float16* __restrict__ act_cond, _Float16* __restrict__ wp1,
    _Float16* __restrict__ wp2, _Float16* __restrict__ wp3,
    _Float16* __restrict__ wp4, _Float16* __restrict__ xg,
    _Float16* __restrict__ wdg, _Float16* __restrict__ pb_all)
{
    int b = blockIdx.x;
    const int t = threadIdx.x;

    if (b < 1164) {   // ---- A: cond pack ----
        const int y = b % 194;     // 0..193
        const int c = b / 194;     // chunk 0..5
        if (t >= PADW) return;
        const bool inb = (y >= 1 && y <= IMG_H && t >= 1 && t <= IMG_W);
        h8 v[4];
#pragma unroll
        for (int j = 0; j < 32; j++)
            ((_Float16*)v)[j] = inb
                ? (_Float16)cond[(size_t)(c * 32 + j) * NPIX + (y - 1) * IMG_W + (t - 1)]
                : (_Float16)0.f;
        h8* d = (h8*)&act_cond[((size_t)c * PPIX + (size_t)y * PADW + t) * 32];
        d[0] = v[0]; d[1] = v[1]; d[2] = v[2]; d[3] = v[3];
        return;
    }
    b -= 1164;

    if (b < 3072) {   // ---- C: xg interior ----
        const int y  = b % 192;
        const int dg = b / 192;
        if (t < 192) {
            h8 v;
#pragma unroll
            for (int chl = 0; chl < 8; chl++)
                v[chl] = (_Float16)x[(size_t)(dg * 8 + chl) * NPIX + y * IMG_W + t];
            *(h8*)&xg[(((size_t)dg * PH + y + 6) * PW + t + 6) * 8] = v;
        }
        return;
    }
    b -= 3072;

    if (b < 108) {    // ---- B: conv weight packs ----
        if      (b < 54) pack_body<192, 64, 64>(b, w1, wp1);
        else if (b < 72) pack_body<64, 64, 64>(b - 54, w2, wp2);
        else if (b < 90) pack_body<64, 64, 64>(b - 72, w3, wp3);
        else             pack_body<64, 448, 432>(b - 90, w4, wp4);
        return;
    }
    b -= 108;

    if (b < 384) {    // ---- D: wdg pack ----
        const int i = b * 256 + t;
        if (i < 16 * 64 * 96) {
            const int ks = i % 96;
            const int rest = i / 96;
            const int co = rest % 64;
            const int dg = rest / 64;
            const int k = ks >> 3, chl = ks & 7;
            float v = 0.f;
            if (ks < 72)
                v = weight[((size_t)co * 128 + dg * 8 + chl) * 9 + k];
            wdg[i] = (_Float16)v;
        }
        return;
    }
    b -= 384;

    if (b < 400) {    // ---- E: xg pad-ring zero (6400 ring px per dg) ----
        const int idx = b * 256 + t;
        if (idx < 16 * 6400) {
            const int dg = idx / 6400;
            int r = idx % 6400;
            int row, col;
            if (r < 1248)      { row = r / 208;              col = r % 208; }
            else if (r < 3328) { r -= 1248; row = 198 + r / 208; col = r % 208; }
            else if (r < 4480) { r -= 3328; row = 6 + r / 6;     col = r % 6; }
            else               { r -= 4480; row = 6 + r / 10;    col = 198 + r % 10; }
            h8 z = {0, 0, 0, 0, 0, 0, 0, 0};
            *(h8*)&xg[(((size_t)dg * PH + row) * PW + col) * 8] = z;
        }
        return;
    }
    b -= 400;

    {                 // ---- F: pb1-3 pad-ring zero (772 px x 6 planes x 4 h8) ----
        const int idx = b * 256 + t;
        if (idx < 6 * 772 * 4) {
            const int px_id = idx >> 2, part = idx & 3;
            const int plane = px_id / 772;
            int r = px_id % 772;
            int y, xx;
            if (r < 194)      { y = 0;            xx = r; }
            else if (r < 388) { y = 193;          xx = r - 194; }
            else if (r < 580) { y = 1 + (r - 388); xx = 0; }
            else              { y = 1 + (r - 580); xx = 193; }
            h8 z = {0, 0, 0, 0, 0, 0, 0, 0};
            *(h8*)&pb_all[((size_t)plane * PPIX + (size_t)y * PADW + xx) * 32 + part * 8] = z;
        }
        return;
    }
}

// ---------------------------------------------------------------------------
// m97-style MFMA conv3x3, R14: COB=32 co per block (was 64). conv4's measured
// limiter was LDS-capped residency (57.9 KB -> 2 blocks/CU, Occupancy 18%,
// MfmaUtil 14%, drain unhidden). Halving the co-range halves w_lds
// (36.9->18.4 KB): conv4 LDS 39.1 KB -> 4 blocks/CU, conv1-3 24.8 KB -> 6.
// 2-barrier chunk schedule UNCHANGED (schedule rewrites failed 3/3: R3/R9/
// R12). Weight staging is a flat-unit loop (per-k would underfill 256t).
// Accumulation order per output unchanged -> bit-identical results.
// XCD-chunked bx swizzle (R13, verified: FETCH 7.8->4.8 MB) retained.
// ACT 1: lrelu -> act-format out. ACT 2: ACTIVATED head (tanh5/sigmoid),
// fp16 seg-major [seg][432][32].
// ---------------------------------------------------------------------------
template<int CHUNKS, int ACT, int COP, int T8, int COB>
__global__ __launch_bounds__(256) void conv_lds_k(
    const _Float16* __restrict__ in,    // [CHUNKS][PPIX][32]
    const _Float16* __restrict__ wpk,   // [CHUNKS][9][COP][32]
    const float* __restrict__ bias,
    _Float16* __restrict__ out)
{
    constexpr int HALO = T8 ? 10 : 18;
    constexpr int NF   = T8 ? 1 : 4;
    constexpr int TDIM = T8 ? 24 : 12;
    constexpr int TSZ  = T8 ? 8 : 16;
    constexpr int INU  = HALO * HALO * 4;   // 16B units in input tile
    constexpr int ROWU = HALO * 4;          // 16B units per halo row
    constexpr int CPX  = (T8 ? 576 : 144) / 8;   // blocks per XCD chunk
    constexpr int MM   = COB / 16;          // MFMA row-frags per wave
    constexpr int WU   = 9 * COB * 4;       // 16B units of weights per chunk

    __shared__ _Float16 in_lds[HALO * HALO * 32];
    __shared__ _Float16 w_lds[9 * COB * 32];

    const int t    = threadIdx.x;
    const int lane = t & 63;
    const int wv   = __builtin_amdgcn_readfirstlane(t >> 6);
    const int col  = lane & 15;
    const int quad = lane >> 4;
    const int bxr  = blockIdx.x;
    const int bx   = (bxr & 7) * CPX + (bxr >> 3);   // XCD-chunked
    const int tx0  = (bx % TDIM) * TSZ;
    const int ty0  = (bx / TDIM) * TSZ;
    const int cobase = blockIdx.y * COB;

    f32x4 acc[MM][NF];
#pragma unroll
    for (int m = 0; m < MM; m++)
#pragma unroll
        for (int s = 0; s < NF; s++) {
            f32x4 z = {0.f, 0.f, 0.f, 0.f};
            acc[m][s] = z;
        }

    for (int c = 0; c < CHUNKS; c++) {
        __syncthreads();   // previous chunk's LDS reads done
        // ---- async stage input halo tile (row-contiguous 16B units) ----
        {
            const char* gbase = (const char*)in + (size_t)c * PPIX * 64;
            char* lbase = (char*)in_lds + (size_t)wv * 64 * 16;
#pragma unroll
            for (int i = 0; i < (INU + 255) / 256; i++) {
                const int j = t + i * 256;
                if (j < INU) {
                    const int row = j / ROWU;
                    const int u   = j - row * ROWU;
                    cp16(gbase + ((size_t)(ty0 + row) * PADW + tx0) * 64 + u * 16,
                         lbase + (size_t)i * 256 * 16);
                }
            }
        }
        // ---- async stage weights: 9 taps x COB co x 64B, flat units ----
        {
            char* lw = (char*)w_lds + (size_t)wv * 64 * 16;
#pragma unroll
            for (int i = 0; i < (WU + 255) / 256; i++) {
                const int j = t + i * 256;
                if (j < WU) {
                    const int k = j / (COB * 4);
                    const int u = j - k * (COB * 4);
                    cp16((const char*)wpk
                             + ((size_t)(c * 9 + k) * COP + cobase) * 64 + (size_t)u * 16,
                         lw + (size_t)i * 256 * 16);
                }
            }
        }
        __syncthreads();   // drains vmcnt(0): staged data visible

        // ---- 9 taps: pure LDS + MFMA ----
#pragma unroll
        for (int k = 0; k < 9; k++) {
            const int ky = k / 3, kx = k % 3;
            h8 af[MM];
#pragma unroll
            for (int m = 0; m < MM; m++)
                af[m] = *(const h8*)&w_lds[(k * COB + m * 16 + col) * 32 + quad * 8];
            h8 bf[NF];
            if (T8) {
                bf[0] = *(const h8*)&in_lds[
                    ((2 * wv + (col >> 3) + ky) * HALO + (col & 7) + kx) * 32 + quad * 8];
            } else {
#pragma unroll
                for (int s = 0; s < NF; s++)
                    bf[s] = *(const h8*)&in_lds[
                        ((4 * wv + s + ky) * HALO + col + kx) * 32 + quad * 8];
            }
#pragma unroll
            for (int m = 0; m < MM; m++)
#pragma unroll
                for (int s = 0; s < NF; s++)
                    acc[m][s] = __builtin_amdgcn_mfma_f32_16x16x32_f16(
                        af[m], bf[s], acc[m][s], 0, 0, 0);
        }
    }

    // ---- epilogue: D col = px, D row = co (quad*4+r) ----
#pragma unroll
    for (int m = 0; m < MM; m++) {
#pragma unroll
        for (int s = 0; s < NF; s++) {
            int gy, gx;
            if (T8) { gy = ty0 + 2 * wv + (col >> 3); gx = tx0 + (col & 7); }
            else    { gy = ty0 + 4 * wv + s;          gx = tx0 + col; }
            const int ca = cobase + m * 16 + quad * 4;   // first of 4 co
            if (ACT == 1) {
                h4 st;
#pragma unroll
                for (int r = 0; r < 4; r++) {
                    float v = acc[m][s][r] + bias[ca + r];
                    st[r] = (_Float16)((v >= 0.f) ? v : 0.1f * v);
                }
                *(h4*)&out[((size_t)(ca >> 5) * PPIX + (size_t)(gy + 1) * PADW + (gx + 1)) * 32
                           + (ca & 31)] = st;
            } else {
#pragma unroll
                for (int r = 0; r < 4; r++) {
                    const int co = ca + r;
                    if (co < 432) {  // ACTIVATED head, fp16 segment-major
                        const int pix = gy * IMG_W + gx;
                        float v = acc[m][s][r] + bias[co];
                        v = (ca < 288) ? act_tanh5(v) : act_sig(v);
                        out[((size_t)(pix >> 5) * 432 + co) * 32 + (pix & 31)] =
                            (_Float16)v;
                    }
                }
            }
        }
    }
}

// ---------------------------------------------------------------------------
// Deformable conv, MFMA version. R10 structure (best measured): 256t,
// 2 barriers/dq, val4 26.6 KB, XCD swizzle, direct seg-major PRE-ACTIVATED
// od reads, global xg gathers. Issue/latency-bound at ~46-50 us (TLP-null
// R4, ILP-null R6, bytes-null R5/R7, LDS-window regressed R9).
// ---------------------------------------------------------------------------
__global__ __launch_bounds__(256) void deform_mfma_k(
    const _Float16* __restrict__ xg,   // [16][PH][PW][8]
    const _Float16* __restrict__ od,   // [1152 seg][432 co][32 px] ACTIVATED
    const _Float16* __restrict__ wdg,  // [16][64][96]
    const float* __restrict__ bias,
    float* __restrict__ out)
{
    __shared__ __align__(16) _Float16 val4[4][32][104];   // 26.6 KB

    const int t    = threadIdx.x;
    const int lane = t & 63;
    const int wv   = __builtin_amdgcn_readfirstlane(t >> 6);
    const int col  = lane & 15;
    const int quad = lane >> 4;
    const int bxr  = blockIdx.x;                    // raw
    const int bx   = (bxr & 7) * 144 + (bxr >> 3);  // XCD-chunked seg id
    const int gy   = bx / 6;
    const int gx0  = (bx % 6) * 32;

    const _Float16* odseg = od + (size_t)bx * 432 * 32;

    // zero pad tail [72..104) once (read range is [0..96))
    for (int i = t; i < 4 * 32 * 4; i += 256) {
        const int dgl = i >> 7;
        const int r   = i & 127;
        const int px  = r >> 2;
        const int j   = r & 3;
        h8 z = {0, 0, 0, 0, 0, 0, 0, 0};
        *(h8*)&val4[dgl][px][72 + 8 * j] = z;
    }

    f32x4 acc[2];
    {
        f32x4 z = {0.f, 0.f, 0.f, 0.f};
        acc[0] = z; acc[1] = z;
    }

    for (int dq = 0; dq < 4; dq++) {
        __syncthreads();   // prev chunk's val4 reads done (covers init too)

        // ---- sampling: od pre-activated (direct reads), xg gathers ----
        for (int idx = t; idx < 1152; idx += 256) {
            const int pxl  = idx & 31;
            const int rest = idx >> 5;      // 0..35
            const int k    = rest % 9;
            const int dgl  = rest / 9;
            const int dg   = dq * 4 + dgl;
            const int rr   = dgl * 9 + k;
            const float oy = (float)odseg[(dq * 72 + 2 * rr) * 32 + pxl];
            const float ox = (float)odseg[(dq * 72 + 2 * rr + 1) * 32 + pxl];
            const float m  = (float)odseg[(288 + dq * 36 + rr) * 32 + pxl];
            const float py  = (float)(gy - 1 + k / 3) + oy;
            const float pxx = (float)(gx0 + pxl - 1 + k % 3) + ox;
            const float y0 = floorf(py), x0 = floorf(pxx);
            const float fy = py - y0, fx = pxx - x0;
            const int iy = (int)y0 + 6, ix = (int)x0 + 6;
            const _Float16* p = xg + (((size_t)dg * PH + iy) * PW + ix) * 8;
            const h8 c00 = *(const h8*)p;
            const h8 c01 = *(const h8*)(p + 8);
            const h8 c10 = *(const h8*)(p + PW * 8);
            const h8 c11 = *(const h8*)(p + PW * 8 + 8);
            const float ey = 1.f - fy, ex = 1.f - fx;
            const _Float16 s00 = (_Float16)(ey * ex * m);
            const _Float16 s01 = (_Float16)(ey * fx * m);
            const _Float16 s10 = (_Float16)(fy * ex * m);
            const _Float16 s11 = (_Float16)(fy * fx * m);
            const h8 v = c00 * s00 + c01 * s01 + c10 * s10 + c11 * s11;
            *(h8*)&val4[dgl][pxl][k * 8] = v;
        }
        __syncthreads();

        // ---- MFMA: 4 dgl x 3 ks x 2 px-frags ----
#pragma unroll
        for (int dgl = 0; dgl < 4; dgl++) {
            const int dg = dq * 4 + dgl;
            const _Float16* wbase = wdg + ((size_t)dg * 64 + wv * 16 + col) * 96;
#pragma unroll
            for (int ks = 0; ks < 3; ks++) {
                const h8 a  = *(const h8*)(wbase + ks * 32 + quad * 8);
                const h8 b0 = *(const h8*)&val4[dgl][col][ks * 32 + quad * 8];
                const h8 b1 = *(const h8*)&val4[dgl][16 + col][ks * 32 + quad * 8];
                acc[0] = __builtin_amdgcn_mfma_f32_16x16x32_f16(a, b0, acc[0], 0, 0, 0);
                acc[1] = __builtin_amdgcn_mfma_f32_16x16x32_f16(a, b1, acc[1], 0, 0, 0);
            }
        }
    }

    const int co = wv * 16 + quad * 4;
#pragma unroll
    for (int n = 0; n < 2; n++) {
        const int gx = gx0 + n * 16 + col;
#pragma unroll
        for (int r = 0; r < 4; r++)
            out[(size_t)(co + r) * NPIX + gy * IMG_W + gx] = acc[n][r] + bias[co + r];
    }
}

// ---------------------------------------------------------------------------
// Launch: 6 dispatches.
// ---------------------------------------------------------------------------
extern "C" void kernel_launch(void* const* d_in, const int* in_sizes, int n_in,
                              void* d_out, int out_size, void* d_ws, size_t ws_size,
                              hipStream_t stream) {
    (void)in_sizes; (void)n_in; (void)out_size; (void)ws_size;

    const float* x      = (const float*)d_in[0];
    const float* cond   = (const float*)d_in[1];
    const float* weight = (const float*)d_in[2];
    const float* bias   = (const float*)d_in[3];
    const float* w1     = (const float*)d_in[4];
    const float* b1     = (const float*)d_in[5];
    const float* w2     = (const float*)d_in[6];
    const float* b2     = (const float*)d_in[7];
    const float* w3     = (const float*)d_in[8];
    const float* b3     = (const float*)d_in[9];
    const float* w4     = (const float*)d_in[10];
    const float* b4     = (const float*)d_in[11];
    float* out = (float*)d_out;

    char* ws = (char*)d_ws;
    size_t off = 0;
    auto take = [&](size_t bytes) -> char* {
        char* p = ws + off;
        off = (off + bytes + 255) & ~(size_t)255;
        return p;
    };
    _Float16* act_cond = (_Float16*)take((size_t)6 * PPIX * 32 * 2);  // conv1 in
    _Float16* pb_all   = (_Float16*)take((size_t)3 * 2 * PPIX * 32 * 2);
    _Float16* pb1 = pb_all;                         // conv1 out [2][PPIX][32]
    _Float16* pb2 = pb1 + (size_t)2 * PPIX * 32;    // conv2 out
    _Float16* pb3 = pb2 + (size_t)2 * PPIX * 32;    // conv3 out
    _Float16* od  = (_Float16*)take((size_t)432 * NPIX * 2);  // [1152][432][32]
    _Float16* wp1 = (_Float16*)take((size_t)54 * 64 * 32 * 2);
    _Float16* wp2 = (_Float16*)take((size_t)18 * 64 * 32 * 2);
    _Float16* wp3 = (_Float16*)take((size_t)18 * 64 * 32 * 2);
    _Float16* wp4 = (_Float16*)take((size_t)18 * 448 * 32 * 2);
    _Float16* xg  = (_Float16*)take((size_t)16 * PH * PW * 8 * 2);
    _Float16* wdg = (_Float16*)take((size_t)16 * 64 * 96 * 2);

    // Fused prep: packs + pad-ring zeroing.
    hipLaunchKernelGGL(prep_all_k, dim3(5201), dim3(256), 0, stream,
                       cond, w1, w2, w3, w4, x, weight,
                       act_cond, wp1, wp2, wp3, wp4, xg, wdg, pb_all);

    // conv1-3: 8x8 tiles, grid(576,2) x 32co. conv4: 16x16 tiles, grid(144,14) x 32co.
    hipLaunchKernelGGL((conv_lds_k<6, 1, 64, 1, 32>),  dim3(576, 2), dim3(256), 0, stream, act_cond, wp1, b1, pb1);
    hipLaunchKernelGGL((conv_lds_k<2, 1, 64, 1, 32>),  dim3(576, 2), dim3(256), 0, stream, pb1, wp2, b2, pb2);
    hipLaunchKernelGGL((conv_lds_k<2, 1, 64, 1, 32>),  dim3(576, 2), dim3(256), 0, stream, pb2, wp3, b3, pb3);
    hipLaunchKernelGGL((conv_lds_k<2, 2, 448, 0, 32>), dim3(144, 14), dim3(256), 0, stream, pb3, wp4, b4, od);
    hipLaunchKernelGGL(deform_mfma_k, dim3(1152), dim3(256), 0, stream, xg, od, wdg, bias, out);
}